// Round 1
// baseline (32.581 us; speedup 1.0000x reference)
//
#include <hip/hip_runtime.h>

// Masked normalized cross-correlation, b=8, c=1, H=W=128, p=9.
// One block per (batch, patch-row). Mask row (120 patches * 81 floats) staged
// to LDS via coalesced float4 loads; x1/x2 9-row slabs staged likewise.
// 2 lanes per patch compute the 5 running sums; shuffle-combine; block
// reduce; one atomicAdd per block into out[b].

#define BATCH 8
#define HH    128
#define WW    128
#define PP    9
#define HP    120
#define WP    120
#define NPATCH (HP * WP)        // 14400
#define PSQ   (PP * PP)         // 81
#define EPSF  1e-5f

__global__ __launch_bounds__(256) void ncc_kernel(const float* __restrict__ x1,
                                                  const float* __restrict__ x2,
                                                  const float* __restrict__ mask,
                                                  float* __restrict__ out)
{
    const int blk = blockIdx.x;          // 0 .. 8*120-1
    const int b   = blk / HP;
    const int i   = blk - b * HP;        // patch row
    const int tid = threadIdx.x;

    __shared__ __align__(16) float m_lds[WP * PSQ];   // 9720 floats = 38880 B
    __shared__ __align__(16) float x1_lds[PP * WW];   // 1152 floats
    __shared__ __align__(16) float x2_lds[PP * WW];   // 1152 floats
    __shared__ float wsum[4];

    // ---- stage mask row (contiguous, 16B-aligned base) ----
    {
        const float4* msrc = reinterpret_cast<const float4*>(
            mask + ((size_t)b * NPATCH + (size_t)i * WP) * PSQ);
        float4* mdst = reinterpret_cast<float4*>(m_lds);
        for (int t = tid; t < (WP * PSQ) / 4; t += 256)   // 2430 float4
            mdst[t] = msrc[t];
    }
    // ---- stage x1/x2 rows i..i+8 (contiguous) ----
    {
        const float4* s1 = reinterpret_cast<const float4*>(x1 + ((size_t)b * HH + i) * WW);
        const float4* s2 = reinterpret_cast<const float4*>(x2 + ((size_t)b * HH + i) * WW);
        float4* d1 = reinterpret_cast<float4*>(x1_lds);
        float4* d2 = reinterpret_cast<float4*>(x2_lds);
        for (int t = tid; t < (PP * WW) / 4; t += 256) {  // 288 float4
            d1[t] = s1[t];
            d2[t] = s2[t];
        }
    }
    __syncthreads();

    // ---- compute: 2 lanes per patch (rows 0..4 / rows 5..8) ----
    float val = 0.0f;
    const int j = tid >> 1;      // patch column
    const int h = tid & 1;       // half selector
    if (j < WP) {
        const int r0 = h ? 5 : 0;
        const int r1 = h ? 9 : 5;
        float sa = 0.f, saa = 0.f, sb = 0.f, sbb = 0.f, sab = 0.f;
        const float* mp = m_lds + j * PSQ + r0 * PP;
        for (int r = r0; r < r1; ++r) {
            const float* x1r = x1_lds + r * WW + j;
            const float* x2r = x2_lds + r * WW + j;
            #pragma unroll
            for (int cc = 0; cc < PP; ++cc) {
                float a  = x1r[cc];
                float bv = x2r[cc] * mp[cc];
                sa += a;
                saa = fmaf(a, a, saa);
                sb += bv;
                sbb = fmaf(bv, bv, sbb);
                sab = fmaf(a, bv, sab);
            }
            mp += PP;
        }
        // combine the two halves of this patch (partner lane = tid^1)
        sa  += __shfl_xor(sa, 1);
        saa += __shfl_xor(saa, 1);
        sb  += __shfl_xor(sb, 1);
        sbb += __shfl_xor(sbb, 1);
        sab += __shfl_xor(sab, 1);
        if (h == 0) {
            const float invN = 1.0f / 81.0f;
            float mua  = sa * invN;
            float mub  = sb * invN;
            float vara = saa * invN - mua * mua + EPSF;
            float varb = sbb * invN - mub * mub + EPSF;
            float cov  = sab - 81.0f * mua * mub;
            val = cov / sqrtf(vara * varb);
        }
    }

    // ---- block reduction ----
    #pragma unroll
    for (int off = 32; off > 0; off >>= 1)
        val += __shfl_down(val, off);
    const int wave = tid >> 6;
    if ((tid & 63) == 0) wsum[wave] = val;
    __syncthreads();
    if (tid == 0) {
        float tot = wsum[0] + wsum[1] + wsum[2] + wsum[3];
        atomicAdd(out + b, tot * (1.0f / (float)(NPATCH * PSQ)));
    }
}

extern "C" void kernel_launch(void* const* d_in, const int* in_sizes, int n_in,
                              void* d_out, int out_size, void* d_ws, size_t ws_size,
                              hipStream_t stream) {
    const float* x1   = (const float*)d_in[0];
    const float* x2   = (const float*)d_in[1];
    const float* mask = (const float*)d_in[2];
    float* out = (float*)d_out;

    hipMemsetAsync(out, 0, out_size * sizeof(float), stream);
    ncc_kernel<<<BATCH * HP, 256, 0, stream>>>(x1, x2, mask, out);
}

// Round 2
// 17.179 us; speedup vs baseline: 1.8965x; 1.8965x over previous
//
#include <hip/hip_runtime.h>

// Masked normalized cross-correlation, b=8, c=1, H=W=128, p=9.
// R1: (a) atomics -> per-block partial stores in d_ws + finalize kernel
//     (single 64B line held all 8 outputs -> ~960 serialized RMWs);
//     (b) staging via __builtin_amdgcn_global_load_lds width=16 (no VGPR
//     round trip, all loads issued up front).
// One block per (batch, patch-row): mask row (120*81 floats) + 9-row x1/x2
// slabs staged to LDS; 2 lanes per patch accumulate 5 sums; shuffle-combine;
// block-reduce; plain store of partial. finalize: 8 blocks x 128t reduce.

#define BATCH 8
#define HH    128
#define WW    128
#define PP    9
#define HP    120
#define WP    120
#define NPATCH (HP * WP)        // 14400
#define PSQ   (PP * PP)         // 81
#define EPSF  1e-5f

__device__ __forceinline__ void gload16(const void* g, void* lds) {
    __builtin_amdgcn_global_load_lds(
        (const __attribute__((address_space(1))) void*)g,
        (__attribute__((address_space(3))) void*)lds, 16, 0, 0);
}

__global__ __launch_bounds__(256) void ncc_kernel(const float* __restrict__ x1,
                                                  const float* __restrict__ x2,
                                                  const float* __restrict__ mask,
                                                  float* __restrict__ part)
{
    const int blk  = blockIdx.x;          // 0 .. 8*120-1
    const int b    = blk / HP;
    const int i    = blk - b * HP;        // patch row
    const int tid  = threadIdx.x;
    const int lane = tid & 63;

    __shared__ __align__(16) float m_lds[WP * PSQ];   // 9720 floats = 38880 B
    __shared__ __align__(16) float x1_lds[PP * WW];   // 1152 floats
    __shared__ __align__(16) float x2_lds[PP * WW];   // 1152 floats
    __shared__ float wsum[4];

    // ---- stage mask row: 2430 float4, direct global->LDS ----
    {
        const float4* msrc = reinterpret_cast<const float4*>(
            mask + ((size_t)b * NPATCH + (size_t)i * WP) * PSQ);
        char* mdst = reinterpret_cast<char*>(m_lds);
        #pragma unroll
        for (int k = 0; k < 10; ++k) {
            int g = k * 256 + tid;                     // float4 index
            if (g < (WP * PSQ) / 4)                    // 2430
                gload16(msrc + g, mdst + (size_t)(g - lane) * 16);
        }
    }
    // ---- stage x1/x2 rows i..i+8 (contiguous, 288 float4 each) ----
    {
        const float4* s1 = reinterpret_cast<const float4*>(x1 + ((size_t)b * HH + i) * WW);
        const float4* s2 = reinterpret_cast<const float4*>(x2 + ((size_t)b * HH + i) * WW);
        char* d1 = reinterpret_cast<char*>(x1_lds);
        char* d2 = reinterpret_cast<char*>(x2_lds);
        #pragma unroll
        for (int k = 0; k < 2; ++k) {
            int g = k * 256 + tid;
            if (g < (PP * WW) / 4) {                   // 288
                gload16(s1 + g, d1 + (size_t)(g - lane) * 16);
                gload16(s2 + g, d2 + (size_t)(g - lane) * 16);
            }
        }
    }
    __syncthreads();   // compiler drains vmcnt(0) here

    // ---- compute: 2 lanes per patch (rows 0..4 / rows 5..8) ----
    float val = 0.0f;
    const int j = tid >> 1;      // patch column
    const int h = tid & 1;       // half selector
    if (j < WP) {
        const int r0 = h ? 5 : 0;
        const int r1 = h ? 9 : 5;
        float sa = 0.f, saa = 0.f, sb = 0.f, sbb = 0.f, sab = 0.f;
        const float* mp = m_lds + j * PSQ + r0 * PP;
        for (int r = r0; r < r1; ++r) {
            const float* x1r = x1_lds + r * WW + j;
            const float* x2r = x2_lds + r * WW + j;
            #pragma unroll
            for (int cc = 0; cc < PP; ++cc) {
                float a  = x1r[cc];
                float bv = x2r[cc] * mp[cc];
                sa += a;
                saa = fmaf(a, a, saa);
                sb += bv;
                sbb = fmaf(bv, bv, sbb);
                sab = fmaf(a, bv, sab);
            }
            mp += PP;
        }
        sa  += __shfl_xor(sa, 1);
        saa += __shfl_xor(saa, 1);
        sb  += __shfl_xor(sb, 1);
        sbb += __shfl_xor(sbb, 1);
        sab += __shfl_xor(sab, 1);
        if (h == 0) {
            const float invN = 1.0f / 81.0f;
            float mua  = sa * invN;
            float mub  = sb * invN;
            float vara = saa * invN - mua * mua + EPSF;
            float varb = sbb * invN - mub * mub + EPSF;
            float cov  = sab - 81.0f * mua * mub;
            val = cov / sqrtf(vara * varb);
        }
    }

    // ---- block reduction -> one plain store per block ----
    #pragma unroll
    for (int off = 32; off > 0; off >>= 1)
        val += __shfl_down(val, off);
    const int wave = tid >> 6;
    if ((tid & 63) == 0) wsum[wave] = val;
    __syncthreads();
    if (tid == 0)
        part[blk] = wsum[0] + wsum[1] + wsum[2] + wsum[3];
}

__global__ __launch_bounds__(128) void finalize_kernel(const float* __restrict__ part,
                                                       float* __restrict__ out)
{
    const int b = blockIdx.x;       // 0..7
    const int t = threadIdx.x;      // 0..127
    float v = (t < HP) ? part[b * HP + t] : 0.0f;
    #pragma unroll
    for (int off = 32; off > 0; off >>= 1)
        v += __shfl_down(v, off);
    __shared__ float s[2];
    if ((t & 63) == 0) s[t >> 6] = v;
    __syncthreads();
    if (t == 0)
        out[b] = (s[0] + s[1]) * (1.0f / ((float)NPATCH * (float)PSQ));
}

extern "C" void kernel_launch(void* const* d_in, const int* in_sizes, int n_in,
                              void* d_out, int out_size, void* d_ws, size_t ws_size,
                              hipStream_t stream) {
    const float* x1   = (const float*)d_in[0];
    const float* x2   = (const float*)d_in[1];
    const float* mask = (const float*)d_in[2];
    float* out  = (float*)d_out;
    float* part = (float*)d_ws;     // 960 floats of scratch

    ncc_kernel<<<BATCH * HP, 256, 0, stream>>>(x1, x2, mask, part);
    finalize_kernel<<<BATCH, 128, 0, stream>>>(part, out);
}